// Round 4
// baseline (922.659 us; speedup 1.0000x reference)
//
#include <hip/hip_runtime.h>
#include <stdint.h>

#define B_ROWS 1024
#define H_DIM  768
#define N_ROWS 100000
#define C_DIM  42
#define NB     32
#define NCHUNK 3125      // 3125*32 = 100000 exactly
#define NP     64        // chunk partitions
#define NY     8         // blocks covering b per chunk (128 rows each)

typedef __attribute__((ext_vector_type(4))) float f32x4;
typedef unsigned long long ull;

__device__ __forceinline__ ull packvi(float v, unsigned n) {
    unsigned u = __float_as_uint(v);
    u = (u & 0x80000000u) ? ~u : (u | 0x80000000u);
    return ((ull)u << 32) | (ull)(~n);
}

// f32x4 -> 4 x fp8(e4m3) packed in one dword
__device__ __forceinline__ int pk8(float4 v) {
    int d = __builtin_amdgcn_cvt_pk_fp8_f32(v.x, v.y, 0, false);
    d     = __builtin_amdgcn_cvt_pk_fp8_f32(v.z, v.w, d, true);
    return d;
}

// LDS byte offset for chunk element (k-step k, k-oct kg, local row n), XOR-swizzled
// so both the stage writes (lanes vary k,kg at fixed n) and the compute reads
// (lanes vary n=fr, kg=kgrp at fixed k) hit all bank pairs evenly (b64 floor).
__device__ __forceinline__ int swz(int k, int kg, int n) {
    return (k * 1024 + kg * 256 + n * 8) ^ ((kg << 3) | ((k & 3) << 5));
}

// ---------------- K1: weak_data f32 -> fp8 fragment-packed A2 ----------------
// element for (row = rg*16+fr, cols k*32+kgrp*8 .. +8) lives at long-index
// ((rg*24 + k)*64 + kgrp*16 + fr)
__global__ void k_convA(const float* __restrict__ wd, int2* __restrict__ A2) {
    int g = blockIdx.x * 256 + threadIdx.x;       // [0, 1024*96)
    int row = g / 96;
    int rem = g - row * 96;
    int k = rem >> 2, kgrp = rem & 3;
    const float* s = wd + row * H_DIM + k * 32 + kgrp * 8;
    float4 v0 = *reinterpret_cast<const float4*>(s);
    float4 v1 = *reinterpret_cast<const float4*>(s + 4);
    int rg = row >> 4, fr = row & 15;
    A2[((rg * 24 + k) * 64 + kgrp * 16 + fr)] = make_int2(pk8(v0), pk8(v1));
}

// ---------------- K2: A-in-regs fp8 GEMM + fused running argmax ----------------
__global__ __launch_bounds__(256, 2) void k_simmax(
    const float* __restrict__ mem,        // [N, 768] f32
    const long* __restrict__ A2,          // fragment-packed fp8
    ull* __restrict__ partial)            // [NP][1024]
{
    __shared__ __align__(16) char ldsB[2][24 * 1024];  // fp8 chunk, dbuf, swizzled
    __shared__ float ldsS[4][NB];                      // sum-of-squares, 4-slot rotation

    const int t    = threadIdx.x;
    const int lane = t & 63;
    const int wv   = t >> 6;          // 0..3
    const int fr   = lane & 15;
    const int kgrp = lane >> 4;       // 0..3
    const int bx   = blockIdx.x;
    const int y    = bx >> 6;         // 0..7   (b-range y*128 .. +128)
    const int p    = bx & 63;         // chunk partition; XCD = p%8 for all y

    // ---- one-time A preload: 2 row-groups x 24 k-steps = 96 VGPRs ----
    const int RG0 = y * 8 + wv * 2;
    long Afr[2][24];
    #pragma unroll
    for (int rg = 0; rg < 2; ++rg) {
        const long* ap = A2 + (size_t)(RG0 + rg) * 24 * 64 + lane;
        #pragma unroll
        for (int k = 0; k < 24; ++k) Afr[rg][k] = ap[k * 64];
    }

    float    bv[2][2][4];
    unsigned bi[2][2][4];
    #pragma unroll
    for (int rg = 0; rg < 2; ++rg)
        #pragma unroll
        for (int nt = 0; nt < 2; ++nt)
            #pragma unroll
            for (int r = 0; r < 4; ++r) { bv[rg][nt][r] = -1e30f; bi[rg][nt][r] = 0u; }

    const int nc = (p < 53) ? 49 : 48;   // 3125 = 48*64 + 53

    // stage chunk c into buffer bb, norms slot ns
    auto stage = [&](int c, int bb, int ns) {
        #pragma unroll 4
        for (int uu = 0; uu < 12; ++uu) {
            int ug = t + 256 * uu;            // [0, 3072)
            int n  = ug / 96;
            int rm = ug - n * 96;
            int k = rm >> 2, kg = rm & 3;
            const float* s = mem + (size_t)(c * NB + n) * H_DIM + k * 32 + kg * 8;
            float4 v0 = *reinterpret_cast<const float4*>(s);
            float4 v1 = *reinterpret_cast<const float4*>(s + 4);
            float ss = v0.x*v0.x + v0.y*v0.y + v0.z*v0.z + v0.w*v0.w
                     + v1.x*v1.x + v1.y*v1.y + v1.z*v1.z + v1.w*v1.w;
            atomicAdd(&ldsS[ns][n], ss);
            *reinterpret_cast<int2*>(&ldsB[bb][swz(k, kg, n)]) =
                make_int2(pk8(v0), pk8(v1));
        }
    };

    // prologue: zero norm slots 0,1; stage chunk(i=0)
    if (t < NB) { ldsS[0][t] = 0.f; ldsS[1][t] = 0.f; }
    __syncthreads();
    stage(p, 0, 0);

    for (int i = 0; i < nc; ++i) {
        __syncthreads();
        if (t < NB) ldsS[(i + 2) & 3][t] = 0.f;     // slot for stage at iter i+1
        if (i + 1 < nc) stage(p + (i + 1) * NP, (i + 1) & 1, (i + 1) & 3);

        // ---- compute current chunk ----
        const int c  = p + i * NP;
        const int bb = i & 1;
        const int ns = i & 3;

        f32x4 acc[2][2];
        #pragma unroll
        for (int rg = 0; rg < 2; ++rg)
            #pragma unroll
            for (int nt = 0; nt < 2; ++nt)
                acc[rg][nt] = (f32x4){0.f, 0.f, 0.f, 0.f};

        #pragma unroll
        for (int k = 0; k < 24; ++k) {
            long bfr0 = *reinterpret_cast<const long*>(&ldsB[bb][swz(k, kgrp, fr)]);
            long bfr1 = *reinterpret_cast<const long*>(&ldsB[bb][swz(k, kgrp, 16 + fr)]);
            #pragma unroll
            for (int rg = 0; rg < 2; ++rg) {
                acc[rg][0] = __builtin_amdgcn_mfma_f32_16x16x32_fp8_fp8(Afr[rg][k], bfr0, acc[rg][0], 0, 0, 0);
                acc[rg][1] = __builtin_amdgcn_mfma_f32_16x16x32_fp8_fp8(Afr[rg][k], bfr1, acc[rg][1], 0, 0, 0);
            }
        }

        float inv0 = __frsqrt_rn(fmaxf(ldsS[ns][fr],      1e-16f));
        float inv1 = __frsqrt_rn(fmaxf(ldsS[ns][16 + fr], 1e-16f));
        const unsigned n0 = (unsigned)(c * NB) + (unsigned)fr;
        #pragma unroll
        for (int rg = 0; rg < 2; ++rg)
            #pragma unroll
            for (int r = 0; r < 4; ++r) {
                float v0 = acc[rg][0][r] * inv0;
                float v1 = acc[rg][1][r] * inv1;
                bool p0 = v0 > bv[rg][0][r];
                bv[rg][0][r] = p0 ? v0 : bv[rg][0][r];
                bi[rg][0][r] = p0 ? n0 : bi[rg][0][r];
                bool p1 = v1 > bv[rg][1][r];
                bv[rg][1][r] = p1 ? v1 : bv[rg][1][r];
                bi[rg][1][r] = p1 ? (n0 + 16) : bi[rg][1][r];
            }
    }

    // ---- once per block: merge nt, reduce across fr, store ----
    #pragma unroll
    for (int rg = 0; rg < 2; ++rg)
        #pragma unroll
        for (int r = 0; r < 4; ++r) {
            ull P0 = packvi(bv[rg][0][r], bi[rg][0][r]);
            ull P1 = packvi(bv[rg][1][r], bi[rg][1][r]);
            ull P  = (P1 > P0) ? P1 : P0;
            #pragma unroll
            for (int s = 1; s < 16; s <<= 1) {
                ull o = __shfl_xor(P, s);
                P = (o > P) ? o : P;
            }
            if (fr == 0) {
                int b = y * 128 + wv * 32 + rg * 16 + kgrp * 4 + r;
                partial[(size_t)p * B_ROWS + b] = P;
            }
        }
}

// ---------------- K3: reduce 64 partials per b, gather + epilogue ----------------
__global__ void k_final(const ull* __restrict__ partial,
                        const float* __restrict__ wlog,
                        const float* __restrict__ llog,
                        float* __restrict__ out)
{
    const int t    = threadIdx.x;
    const int lane = t & 63;
    const int wv   = t >> 6;
    const int b    = blockIdx.x * 4 + wv;

    ull P = partial[(size_t)lane * B_ROWS + b];
    #pragma unroll
    for (int s = 1; s < 64; s <<= 1) {
        ull o = __shfl_xor(P, s);
        P = (o > P) ? o : P;
    }
    int idx = (int)(~(unsigned)(P & 0xFFFFFFFFull));
    if (lane < C_DIM)
        out[b * C_DIM + lane] = 0.7f * llog[(size_t)idx * C_DIM + lane]
                              - 99999.0f * wlog[b * C_DIM + lane];
}

extern "C" void kernel_launch(void* const* d_in, const int* in_sizes, int n_in,
                              void* d_out, int out_size, void* d_ws, size_t ws_size,
                              hipStream_t stream) {
    const float* weak_data   = (const float*)d_in[0];
    const float* weak_logits = (const float*)d_in[1];
    const float* mem         = (const float*)d_in[2];
    const float* llog        = (const float*)d_in[3];
    float* out = (float*)d_out;

    int2* A2      = (int2*)d_ws;                               // 768 KB
    ull*  partial = (ull*)((char*)d_ws + 0x100000);            // @1 MB, 512 KB

    k_convA <<<384, 256, 0, stream>>>(weak_data, A2);
    k_simmax<<<NY * NP, 256, 0, stream>>>(mem, (const long*)A2, partial);
    k_final <<<256, 256, 0, stream>>>(partial, weak_logits, llog, out);
}